// Round 4
// baseline (1388.175 us; speedup 1.0000x reference)
//
#include <hip/hip_runtime.h>

#define T_STEPS 1000
#define NB 256
#define DZ 64
#define DH 256
#define DS 16
#define CHUNK 16
#define NCHUNK 63   // ceil(1000/16): last chunk computes 8 garbage steps, unstored

// LDS-only barrier: drains lgkmcnt (LDS ordering) but NOT vmcnt.
// Safe here: all global loads target private registers and global stores are
// never read back by the kernel.
__device__ __forceinline__ void barrier_lgkm() {
    asm volatile("s_waitcnt lgkmcnt(0)\n\ts_barrier" ::: "memory");
}

// ---- AGPR residency for loop-invariant weights --------------------------
// Rounds 2-3 lesson: the VGPR allocator refuses to keep a 128-float
// loop-invariant array live (remats from L2 / spills to scratch -> 32 TB/s
// L2 stream = the bottleneck). The AGPR class bypasses that heuristic:
// values parked via v_accvgpr_write stay in the accumulator file (132 AGPRs
// used; MFMA kernels routinely hold 128+).
__device__ __forceinline__ void ag_store(float& a, float v) {
    asm("v_accvgpr_write_b32 %0, %1" : "=a"(a) : "v"(v));
}
// volatile: MUST stay inside the loop (a hoisted read would re-create the
// 128-float VGPR liveness problem).
__device__ __forceinline__ float ag_load(const float& a) {
    float v;
    asm volatile("v_accvgpr_read_b32 %0, %1" : "=v"(v) : "a"(a));
    return v;
}

// One block per trial b; 256 threads = 4 waves; 1 block/CU (grid=256).
// Phase 1: thread tid owns h=tid: Wz[h] = W1[b][h][:]·z  (W1 row in AGPRs, z broadcast from LDS)
// Phase 2: wave w, lane l: output j2=16w+(l&15), h-chunk c2=l>>4 (64 h each);
//          C·s folded in per-replica (4 s-elems each); butterfly (xor 16, 32).
// Epilogue: every lane finishes z_new[j2]; lanes l<16 publish. 2 barriers/step.
__global__ __launch_bounds__(256, 1)
void plrnn_scan(const float* __restrict__ z0, const float* __restrict__ s,
                const float* __restrict__ A,  const float* __restrict__ W1,
                const float* __restrict__ W2, const float* __restrict__ h1,
                const float* __restrict__ h2, const float* __restrict__ C,
                float* __restrict__ out)
{
    const int tid = threadIdx.x;
    const int b   = blockIdx.x;
    const int w   = tid >> 6;
    const int l   = tid & 63;
    const int l4  = l & 15;
    const int c2  = l >> 4;
    const int j2  = (w << 4) | l4;

    __shared__ __align__(16) float z_sh[DZ];
    __shared__ __align__(16) float za_sh[DH + 16];   // +4 skew per 64-chunk -> conflict-free phase-2 reads
    __shared__ __align__(16) float s_sh[CHUNK * DS]; // 16 steps of s[t][b][0..15]

    // ---- load weights once, park in AGPRs ----
    float wa1[DZ];    // W1[b][tid][0..63]
    {
        const float4* p = (const float4*)(W1 + (size_t)b * DH * DZ + (size_t)tid * DZ);
        #pragma unroll
        for (int k = 0; k < 16; ++k) {
            float4 v = p[k];
            ag_store(wa1[4*k+0], v.x); ag_store(wa1[4*k+1], v.y);
            ag_store(wa1[4*k+2], v.z); ag_store(wa1[4*k+3], v.w);
        }
    }
    float wa2[DZ];    // W2[b][j2][64*c2 .. 64*c2+63]
    {
        const float4* p = (const float4*)(W2 + (size_t)b * DZ * DH + (size_t)j2 * DH + (size_t)c2 * 64);
        #pragma unroll
        for (int k = 0; k < 16; ++k) {
            float4 v = p[k];
            ag_store(wa2[4*k+0], v.x); ag_store(wa2[4*k+1], v.y);
            ag_store(wa2[4*k+2], v.z); ag_store(wa2[4*k+3], v.w);
        }
    }
    float ca[4];      // C[j2][4*c2 .. 4*c2+3] (this replica's quarter of the s-dot)
    {
        const float4* p = (const float4*)(C + j2 * DS + c2 * 4);
        float4 v = p[0];
        ag_store(ca[0], v.x); ag_store(ca[1], v.y);
        ag_store(ca[2], v.z); ag_store(ca[3], v.w);
    }

    const float h1r = h1[tid];
    const float Ar  = A[j2];
    const float h2r = h2[j2];
    float zr = z0[b * DZ + j2];          // z state in register (replicated x4 lanes per j2)

    if (l < 16) z_sh[j2] = zr;

    // s prefetch: thread tid holds s[t0+srow][b][scol] for the NEXT chunk
    const int srow = tid >> 4, scol = tid & 15;
    float sreg = s[(size_t)min(srow, T_STEPS - 1) * NB * DS + (size_t)b * DS + scol];

    __syncthreads();

    for (int ci = 0; ci < NCHUNK; ++ci) {
        const int t0 = ci * CHUNK;
        s_sh[tid] = sreg;                 // visible after this step's barrier A
        {
            int tl = min(t0 + CHUNK + srow, T_STEPS - 1);
            sreg = s[(size_t)tl * NB * DS + (size_t)b * DS + scol];
        }

        for (int tt = 0; tt < CHUNK; ++tt) {
            // ---- phase 1: Wz[tid] = W1 row (AGPR) · z (LDS broadcast) ----
            const float4* z4 = (const float4*)z_sh;
            float a0 = 0.f, a1 = 0.f, a2 = 0.f, a3 = 0.f;
            #pragma unroll
            for (int k = 0; k < 16; ++k) {
                float4 zv = z4[k];                    // same-address broadcast
                a0 = fmaf(ag_load(wa1[4*k+0]), zv.x, a0);
                a1 = fmaf(ag_load(wa1[4*k+1]), zv.y, a1);
                a2 = fmaf(ag_load(wa1[4*k+2]), zv.z, a2);
                a3 = fmaf(ag_load(wa1[4*k+3]), zv.w, a3);
            }
            float Wz = (a0 + a1) + (a2 + a3);
            float za = fmaxf(Wz + h1r, 0.f) - fmaxf(Wz, 0.f);
            za_sh[tid + (w << 2)] = za;               // skewed store
            barrier_lgkm();                           // A: za_sh (+ s_sh at chunk start) visible

            // ---- phase 2: partial over h-chunk c2 for output j2 ----
            const float4* q4 = (const float4*)(za_sh + c2 * 68);  // 68-float skewed rows
            float p0 = 0.f, p1 = 0.f, p2 = 0.f, p3 = 0.f;
            #pragma unroll
            for (int k = 0; k < 16; ++k) {
                float4 v = q4[k];                     // 4 bank-disjoint broadcast groups
                p0 = fmaf(ag_load(wa2[4*k+0]), v.x, p0);
                p1 = fmaf(ag_load(wa2[4*k+1]), v.y, p1);
                p2 = fmaf(ag_load(wa2[4*k+2]), v.z, p2);
                p3 = fmaf(ag_load(wa2[4*k+3]), v.w, p3);
            }
            // fold this replica's quarter of C·s_t into the partial
            {
                const float4* s4 = (const float4*)(s_sh + tt * DS + c2 * 4);
                float4 sv = s4[0];                    // 4 bank-disjoint broadcast groups
                p0 = fmaf(ag_load(ca[0]), sv.x, p0);
                p1 = fmaf(ag_load(ca[1]), sv.y, p1);
                p2 = fmaf(ag_load(ca[2]), sv.z, p2);
                p3 = fmaf(ag_load(ca[3]), sv.w, p3);
            }
            float p = (p0 + p1) + (p2 + p3);
            p += __shfl_xor(p, 16);                   // reduce across c2 (lane bits 4,5)
            p += __shfl_xor(p, 32);

            // ---- epilogue (all lanes have full W2·za + C·s for j2) ----
            float zn = fmaf(Ar, zr, p + h2r);
            zr = zn;
            const int t = t0 + tt;
            if (l < 16) {
                z_sh[j2] = zn;
                if (t < T_STEPS)
                    out[(size_t)t * NB * DZ + (size_t)b * DZ + j2] = zn;  // fire-and-forget
            }
            barrier_lgkm();                           // B: z_sh update visible for next phase 1
        }
    }
}

extern "C" void kernel_launch(void* const* d_in, const int* in_sizes, int n_in,
                              void* d_out, int out_size, void* d_ws, size_t ws_size,
                              hipStream_t stream) {
    const float* z0p = (const float*)d_in[0];
    const float* sp  = (const float*)d_in[1];
    const float* Ap  = (const float*)d_in[2];
    const float* W1p = (const float*)d_in[3];
    const float* W2p = (const float*)d_in[4];
    const float* h1p = (const float*)d_in[5];
    const float* h2p = (const float*)d_in[6];
    const float* Cp  = (const float*)d_in[7];

    plrnn_scan<<<dim3(NB), dim3(256), 0, stream>>>(z0p, sp, Ap, W1p, W2p, h1p, h2p, Cp,
                                                   (float*)d_out);
}

// Round 5
// 714.250 us; speedup vs baseline: 1.9435x; 1.9435x over previous
//
#include <hip/hip_runtime.h>

#define T_STEPS 1000
#define NB 256
#define DZ 64
#define DH 256
#define DS 16
#define CHUNK 32
#define NCHUNK 32   // 32*32 = 1024 >= 1000; trailing 24 steps computed, unstored

// LDS-only barrier: drains lgkmcnt (LDS ordering) but NOT vmcnt.
// Safe: global loads land in private regs; global stores are never read back.
__device__ __forceinline__ void barrier_lgkm() {
    asm volatile("s_waitcnt lgkmcnt(0)\n\ts_barrier" ::: "memory");
}

// One block per trial b; 512 threads = 8 waves = 2 waves/SIMD (latency hiding).
// Phase 1: lane-pair (2 threads) owns h=tid>>1; each half does 32 MACs of
//          W1[b][h][:]·z, combined with shfl_xor(1). Even half writes za_sh.
// Phase 2: wave w, lane l: output j=(w<<3)|(l&7), replica r=l>>3 does 32 MACs
//          of W2[b][j][32r:32r+32]·za + 2 MACs of C[j][2r:2r+2]·s_t;
//          shfl_xor(8,16,32) completes both dots. All lanes form z_new[j].
// 66 loop-invariant floats/thread (W1 32 + W2 32 + C 2) -> RA keeps resident.
// 2 LDS-only barriers/step.
__global__ __launch_bounds__(512, 2)
void plrnn_scan(const float* __restrict__ z0, const float* __restrict__ s,
                const float* __restrict__ A,  const float* __restrict__ W1,
                const float* __restrict__ W2, const float* __restrict__ h1,
                const float* __restrict__ h2, const float* __restrict__ C,
                float* __restrict__ out)
{
    const int tid  = threadIdx.x;
    const int b    = blockIdx.x;
    const int w    = tid >> 6;
    const int l    = tid & 63;
    const int h    = tid >> 1;          // phase-1 hidden unit owned by the pair
    const int half = tid & 1;           // which 32-wide half of the dot
    const int j    = (w << 3) | (l & 7);// phase-2 z output
    const int r    = l >> 3;            // phase-2 replica (h-range [32r,32r+32))

    __shared__ __align__(16) float z_sh[DZ];
    __shared__ __align__(16) float za_sh[284];        // skew +4 per 32-chunk: idx = h + (h>>5)*4
    __shared__ __align__(16) float s_sh[CHUNK * DS];  // 32 steps of s[t][b][0..15]

    // ---- loop-invariant weights (66 floats/thread) ----
    float4 w1v[8];   // W1[b][h][32*half .. 32*half+31]
    {
        const float4* p = (const float4*)(W1 + (size_t)b * DH * DZ + (size_t)h * DZ + half * 32);
        #pragma unroll
        for (int k = 0; k < 8; ++k) w1v[k] = p[k];
    }
    float4 w2v[8];   // W2[b][j][32*r .. 32*r+31]
    {
        const float4* p = (const float4*)(W2 + (size_t)b * DZ * DH + (size_t)j * DH + r * 32);
        #pragma unroll
        for (int k = 0; k < 8; ++k) w2v[k] = p[k];
    }
    const float c0 = C[j * DS + 2 * r];
    const float c1 = C[j * DS + 2 * r + 1];
    const float h1r = h1[h];
    const float Ar  = A[j];
    const float h2r = h2[j];
    float zr = z0[b * DZ + j];          // z state, replicated across the 8 replicas of j

    if (l < 8) z_sh[j] = zr;            // r==0 lanes cover all 64 j across 8 waves

    // s prefetch: thread tid holds s[t0+srow][b][scol] for the NEXT chunk (32-step lead)
    const int srow = tid >> 4, scol = tid & 15;
    float sreg = s[(size_t)min(srow, T_STEPS - 1) * NB * DS + (size_t)b * DS + scol];

    const int zi = h + ((h >> 5) << 2); // skewed za_sh index for phase-1 store

    __syncthreads();

    for (int ci = 0; ci < NCHUNK; ++ci) {
        const int t0 = ci * CHUNK;
        s_sh[tid] = sreg;               // visible after this step's barrier A
        {
            int tl = min(t0 + CHUNK + srow, T_STEPS - 1);
            sreg = s[(size_t)tl * NB * DS + (size_t)b * DS + scol];
        }

        #pragma unroll 4
        for (int tt = 0; tt < CHUNK; ++tt) {
            // ---- phase 1: Wz[h] ----
            const float4* z4 = (const float4*)(z_sh + half * 32);
            float a0 = 0.f, a1 = 0.f, a2 = 0.f, a3 = 0.f;
            #pragma unroll
            for (int k = 0; k < 8; ++k) {
                float4 zv = z4[k];      // 2 addrs/bank-quad (even/odd) = free 2-way
                a0 = fmaf(w1v[k].x, zv.x, a0);
                a1 = fmaf(w1v[k].y, zv.y, a1);
                a2 = fmaf(w1v[k].z, zv.z, a2);
                a3 = fmaf(w1v[k].w, zv.w, a3);
            }
            float p1 = (a0 + a1) + (a2 + a3);
            p1 += __shfl_xor(p1, 1);    // combine the two 32-halves
            float za = fmaxf(p1 + h1r, 0.f) - fmaxf(p1, 0.f);
            if (half == 0) za_sh[zi] = za;   // 32 consecutive (skewed) floats/wave: conflict-free
            barrier_lgkm();             // A: za_sh (+ s_sh at chunk start) visible

            // ---- phase 2: partial over h-range [32r,32r+32) for output j ----
            const float4* q4 = (const float4*)(za_sh + 36 * r);  // skew makes replica groups bank-disjoint
            float p0 = 0.f, q1 = 0.f, q2 = 0.f, q3 = 0.f;
            #pragma unroll
            for (int k = 0; k < 8; ++k) {
                float4 v = q4[k];
                p0 = fmaf(w2v[k].x, v.x, p0);
                q1 = fmaf(w2v[k].y, v.y, q1);
                q2 = fmaf(w2v[k].z, v.z, q2);
                q3 = fmaf(w2v[k].w, v.w, q3);
            }
            // fold this replica's 2-element slice of C·s_t
            {
                const float2* sq = (const float2*)(s_sh + tt * DS + 2 * r);
                float2 sv = *sq;
                p0 = fmaf(c0, sv.x, p0);
                q1 = fmaf(c1, sv.y, q1);
            }
            float p = (p0 + q1) + (q2 + q3);
            p += __shfl_xor(p, 8);      // reduce across 8 replicas
            p += __shfl_xor(p, 16);
            p += __shfl_xor(p, 32);

            // ---- epilogue: all lanes hold full W2·za + C·s for j ----
            float zn = fmaf(Ar, zr, p + h2r);
            zr = zn;
            const int t = t0 + tt;
            if (r == 0) {
                z_sh[j] = zn;
                if (t < T_STEPS)
                    out[(size_t)t * NB * DZ + (size_t)b * DZ + j] = zn;  // fire-and-forget
            }
            barrier_lgkm();             // B: z_sh update visible for next phase 1
        }
    }
}

extern "C" void kernel_launch(void* const* d_in, const int* in_sizes, int n_in,
                              void* d_out, int out_size, void* d_ws, size_t ws_size,
                              hipStream_t stream) {
    const float* z0p = (const float*)d_in[0];
    const float* sp  = (const float*)d_in[1];
    const float* Ap  = (const float*)d_in[2];
    const float* W1p = (const float*)d_in[3];
    const float* W2p = (const float*)d_in[4];
    const float* h1p = (const float*)d_in[5];
    const float* h2p = (const float*)d_in[6];
    const float* Cp  = (const float*)d_in[7];

    plrnn_scan<<<dim3(NB), dim3(512), 0, stream>>>(z0p, sp, Ap, W1p, W2p, h1p, h2p, Cp,
                                                   (float*)d_out);
}

// Round 6
// 706.263 us; speedup vs baseline: 1.9655x; 1.0113x over previous
//
#include <hip/hip_runtime.h>

#define T_STEPS 1000
#define NB 256
#define DZ 64
#define DH 256
#define DS 16
#define CHUNK 32
#define NCHUNK 32   // 32*32 = 1024 >= 1000; trailing 24 steps computed, unstored

// LDS-only barrier: drains lgkmcnt (LDS ordering) but NOT vmcnt.
// Safe: global loads land in private regs; global stores are never read back.
__device__ __forceinline__ void barrier_lgkm() {
    asm volatile("s_waitcnt lgkmcnt(0)\n\ts_barrier" ::: "memory");
}

// Park a loop-invariant value in the AGPR class. Rounds 2-5 lesson: the VGPR
// allocator refuses to keep loop-invariant weight arrays live (remats the
// global loads every step -> ~470 cyc/step of excess VALU issue + vmem). The
// empty asm makes the value opaque (remat impossible) and the 'a' class is
// free real estate on gfx950's unified file. NON-volatile, outside the loop:
// the compiler may source AGPRs directly in v_fmac or insert cheap
// accvgpr_read copies -- both beat remat (round-4's mistake was VOLATILE
// reads at 1 wave/SIMD).
__device__ __forceinline__ void pin_a(float& x) {
    asm volatile("" : "+a"(x));
}

// One block per trial b; 512 threads = 8 waves = 2 waves/SIMD (latency hiding).
// Phase 1: lane-pair (2 threads) owns h=tid>>1; each half does 32 MACs of
//          W1[b][h][:]·z, combined with shfl_xor(1). Even half writes za_sh.
// Phase 2: wave w, lane l: output j=(w<<3)|(l&7), replica r=l>>3 does 32 MACs
//          of W2[b][j][32r:32r+32]·za + 2 MACs of C[j][2r:2r+2]·s_t;
//          shfl_xor(8,16,32) completes both dots. All lanes form z_new[j].
// 64 weight floats/thread parked in AGPRs; 2 LDS-only barriers/step.
__global__ __launch_bounds__(512, 2)
void plrnn_scan(const float* __restrict__ z0, const float* __restrict__ s,
                const float* __restrict__ A,  const float* __restrict__ W1,
                const float* __restrict__ W2, const float* __restrict__ h1,
                const float* __restrict__ h2, const float* __restrict__ C,
                float* __restrict__ out)
{
    const int tid  = threadIdx.x;
    const int b    = blockIdx.x;
    const int w    = tid >> 6;
    const int l    = tid & 63;
    const int h    = tid >> 1;          // phase-1 hidden unit owned by the pair
    const int half = tid & 1;           // which 32-wide half of the dot
    const int j    = (w << 3) | (l & 7);// phase-2 z output
    const int r    = l >> 3;            // phase-2 replica (h-range [32r,32r+32))

    __shared__ __align__(16) float z_sh[DZ];
    __shared__ __align__(16) float za_sh[284];        // skew +4 per 32-chunk: idx = h + (h>>5)*4
    __shared__ __align__(16) float s_sh[CHUNK * DS];  // 32 steps of s[t][b][0..15]

    // ---- loop-invariant weights -> AGPR class ----
    float4 w1v[8];   // W1[b][h][32*half .. 32*half+31]
    {
        const float4* p = (const float4*)(W1 + (size_t)b * DH * DZ + (size_t)h * DZ + half * 32);
        #pragma unroll
        for (int k = 0; k < 8; ++k) w1v[k] = p[k];
    }
    float4 w2v[8];   // W2[b][j][32*r .. 32*r+31]
    {
        const float4* p = (const float4*)(W2 + (size_t)b * DZ * DH + (size_t)j * DH + r * 32);
        #pragma unroll
        for (int k = 0; k < 8; ++k) w2v[k] = p[k];
    }
    #pragma unroll
    for (int k = 0; k < 8; ++k) {
        pin_a(w1v[k].x); pin_a(w1v[k].y); pin_a(w1v[k].z); pin_a(w1v[k].w);
        pin_a(w2v[k].x); pin_a(w2v[k].y); pin_a(w2v[k].z); pin_a(w2v[k].w);
    }

    const float c0 = C[j * DS + 2 * r];
    const float c1 = C[j * DS + 2 * r + 1];
    const float h1r = h1[h];
    const float Ar  = A[j];
    const float h2r = h2[j];
    float zr = z0[b * DZ + j];          // z state, replicated across the 8 replicas of j

    if (l < 8) z_sh[j] = zr;            // r==0 lanes cover all 64 j across 8 waves

    // s prefetch: thread tid holds s[t0+srow][b][scol] for the NEXT chunk (32-step lead)
    const int srow = tid >> 4, scol = tid & 15;
    float sreg = s[(size_t)min(srow, T_STEPS - 1) * NB * DS + (size_t)b * DS + scol];

    const int zi = h + ((h >> 5) << 2); // skewed za_sh index for phase-1 store

    __syncthreads();

    for (int ci = 0; ci < NCHUNK; ++ci) {
        const int t0 = ci * CHUNK;
        s_sh[tid] = sreg;               // visible after this step's barrier A
        {
            int tl = min(t0 + CHUNK + srow, T_STEPS - 1);
            sreg = s[(size_t)tl * NB * DS + (size_t)b * DS + scol];
        }

        #pragma unroll 4
        for (int tt = 0; tt < CHUNK; ++tt) {
            // ---- phase 1: Wz[h] ----
            const float4* z4 = (const float4*)(z_sh + half * 32);
            float a0 = 0.f, a1 = 0.f, a2 = 0.f, a3 = 0.f;
            #pragma unroll
            for (int k = 0; k < 8; ++k) {
                float4 zv = z4[k];      // 2 addrs/bank-quad (even/odd) = free 2-way
                a0 = fmaf(w1v[k].x, zv.x, a0);
                a1 = fmaf(w1v[k].y, zv.y, a1);
                a2 = fmaf(w1v[k].z, zv.z, a2);
                a3 = fmaf(w1v[k].w, zv.w, a3);
            }
            float p1 = (a0 + a1) + (a2 + a3);
            p1 += __shfl_xor(p1, 1);    // combine the two 32-halves
            float za = fmaxf(p1 + h1r, 0.f) - fmaxf(p1, 0.f);
            if (half == 0) za_sh[zi] = za;   // 32 consecutive (skewed) floats/wave: conflict-free
            barrier_lgkm();             // A: za_sh (+ s_sh at chunk start) visible

            // ---- phase 2: partial over h-range [32r,32r+32) for output j ----
            const float4* q4 = (const float4*)(za_sh + 36 * r);  // skew makes replica groups bank-disjoint
            float p0 = 0.f, q1 = 0.f, q2 = 0.f, q3 = 0.f;
            #pragma unroll
            for (int k = 0; k < 8; ++k) {
                float4 v = q4[k];
                p0 = fmaf(w2v[k].x, v.x, p0);
                q1 = fmaf(w2v[k].y, v.y, q1);
                q2 = fmaf(w2v[k].z, v.z, q2);
                q3 = fmaf(w2v[k].w, v.w, q3);
            }
            // fold this replica's 2-element slice of C·s_t
            {
                const float2* sq = (const float2*)(s_sh + tt * DS + 2 * r);
                float2 sv = *sq;
                p0 = fmaf(c0, sv.x, p0);
                q1 = fmaf(c1, sv.y, q1);
            }
            float p = (p0 + q1) + (q2 + q3);
            p += __shfl_xor(p, 8);      // reduce across 8 replicas
            p += __shfl_xor(p, 16);
            p += __shfl_xor(p, 32);

            // ---- epilogue: all lanes hold full W2·za + C·s for j ----
            float zn = fmaf(Ar, zr, p + h2r);
            zr = zn;
            const int t = t0 + tt;
            if (r == 0) {
                z_sh[j] = zn;
                if (t < T_STEPS)
                    out[(size_t)t * NB * DZ + (size_t)b * DZ + j] = zn;  // fire-and-forget
            }
            barrier_lgkm();             // B: z_sh update visible for next phase 1
        }
    }
}

extern "C" void kernel_launch(void* const* d_in, const int* in_sizes, int n_in,
                              void* d_out, int out_size, void* d_ws, size_t ws_size,
                              hipStream_t stream) {
    const float* z0p = (const float*)d_in[0];
    const float* sp  = (const float*)d_in[1];
    const float* Ap  = (const float*)d_in[2];
    const float* W1p = (const float*)d_in[3];
    const float* W2p = (const float*)d_in[4];
    const float* h1p = (const float*)d_in[5];
    const float* h2p = (const float*)d_in[6];
    const float* Cp  = (const float*)d_in[7];

    plrnn_scan<<<dim3(NB), dim3(512), 0, stream>>>(z0p, sp, Ap, W1p, W2p, h1p, h2p, Cp,
                                                   (float*)d_out);
}

// Round 7
// 639.390 us; speedup vs baseline: 2.1711x; 1.1046x over previous
//
#include <hip/hip_runtime.h>

#define T_STEPS 1000
#define NB 256
#define DZ 64
#define DH 256
#define DS 16
#define CHUNK 32
#define NCHUNK 32   // 32*32 = 1024 >= 1000; trailing 24 steps computed, unstored

// LDS-only barrier: drains lgkmcnt (LDS ordering) but NOT vmcnt.
// Safe: global loads land in private regs; global stores are never read back.
__device__ __forceinline__ void barrier_lgkm() {
    asm volatile("s_waitcnt lgkmcnt(0)\n\ts_barrier" ::: "memory");
}

// VALU-pipe cross-lane add via DPP (no LDS traffic, fuses to v_add_f32_dpp).
// CTRL: 0xB1 = quad_perm[1,0,3,2] (xor1); 0x121/0x122/0x124/0x128 = row_ror 1/2/4/8.
template<int CTRL>
__device__ __forceinline__ float dpp_add(float x) {
    int y = __builtin_amdgcn_update_dpp(0, __float_as_int(x), CTRL, 0xF, 0xF, true);
    return x + __int_as_float(y);
}
// Sum across the 16 lanes of a DPP row (every lane ends with the row total).
__device__ __forceinline__ float row16_allsum(float x) {
    x = dpp_add<0x128>(x);   // += ror8
    x = dpp_add<0x124>(x);   // += ror4
    x = dpp_add<0x122>(x);   // += ror2
    x = dpp_add<0x121>(x);   // += ror1
    return x;
}

// One block per trial b; 512 threads = 8 waves = 2 waves/SIMD.
// amdgpu_waves_per_eu(2,2): pins the register allocator's DESIRED occupancy to
// exactly 2 waves/EU (256-VGPR budget) so it stops rematerializing /
// AGPR-copying the 64 loop-invariant weight floats (rounds 2-6 lesson:
// launch_bounds' min-waves alone does NOT lower the RA's occupancy target).
//
// Phase 1: lane-pair owns h=tid>>1; each half does 32 MACs of W1[b][h][:]·z,
//          combined with a quad_perm-xor1 DPP add. Even half writes za_sh.
// Phase 2: 16-lane row R = 4w + (l>>4) owns the j-PAIR {2R, 2R+1} over the
//          FULL h range; lane r4=l&15 covers h in [16*r4, 16*r4+16) (4 b128
//          reads, skewed 2-way = free) + C[j][r4]*s_t[r4]; row_ror DPP
//          rotation-reduce gives every lane both complete sums. No ds_swizzle.
// 2 LDS-only barriers/step.
__global__ __launch_bounds__(512)
__attribute__((amdgpu_waves_per_eu(2, 2)))
void plrnn_scan(const float* __restrict__ z0, const float* __restrict__ s,
                const float* __restrict__ A,  const float* __restrict__ W1,
                const float* __restrict__ W2, const float* __restrict__ h1,
                const float* __restrict__ h2, const float* __restrict__ C,
                float* __restrict__ out)
{
    const int tid  = threadIdx.x;
    const int b    = blockIdx.x;
    const int w    = tid >> 6;
    const int l    = tid & 63;
    const int h    = tid >> 1;            // phase-1 hidden unit (pair-owned)
    const int half = tid & 1;             // which 32-wide half of the W1 dot
    const int R    = (w << 2) | (l >> 4); // phase-2 row id, 0..31
    const int r4   = l & 15;              // lane within row = 16-h slice
    const int j0   = 2 * R;               // row's two z outputs
    const int j1   = 2 * R + 1;

    __shared__ __align__(16) float z_sh[DZ];
    __shared__ __align__(16) float za_sh[320];        // skew: idx = h + (h>>4)*4
    __shared__ __align__(16) float s_sh[CHUNK * DS];  // 32 steps of s[t][b][0..15]

    // ---- loop-invariant weights (64 floats + C pair) ----
    float4 w1v[8];    // W1[b][h][32*half .. +32)
    {
        const float4* p = (const float4*)(W1 + (size_t)b * DH * DZ + (size_t)h * DZ + half * 32);
        #pragma unroll
        for (int k = 0; k < 8; ++k) w1v[k] = p[k];
    }
    float4 w2a[4];    // W2[b][j0][16*r4 .. +16)
    float4 w2b[4];    // W2[b][j1][16*r4 .. +16)
    {
        const float4* p0 = (const float4*)(W2 + (size_t)b * DZ * DH + (size_t)j0 * DH + 16 * r4);
        const float4* p1 = (const float4*)(W2 + (size_t)b * DZ * DH + (size_t)j1 * DH + 16 * r4);
        #pragma unroll
        for (int k = 0; k < 4; ++k) { w2a[k] = p0[k]; w2b[k] = p1[k]; }
    }
    const float c0  = C[j0 * DS + r4];    // this lane's slice of C·s for j0/j1
    const float c1  = C[j1 * DS + r4];
    const float h1r = h1[h];
    const float A0  = A[j0],  A1  = A[j1];
    const float h20 = h2[j0], h21 = h2[j1];
    float zr0 = z0[b * DZ + j0];          // z state for the row's pair (replicated x16)
    float zr1 = z0[b * DZ + j1];

    if (tid < DZ) z_sh[tid] = z0[b * DZ + tid];

    // s prefetch: thread tid holds s[t0+srow][b][scol] for the NEXT chunk
    const int srow = tid >> 4, scol = tid & 15;
    float sreg = s[(size_t)min(srow, T_STEPS - 1) * NB * DS + (size_t)b * DS + scol];

    const int zi = h + ((h >> 4) << 2);   // skewed za_sh index for phase-1 store

    __syncthreads();

    for (int ci = 0; ci < NCHUNK; ++ci) {
        const int t0 = ci * CHUNK;
        s_sh[tid] = sreg;                 // visible after this step's barrier A
        {
            int tl = min(t0 + CHUNK + srow, T_STEPS - 1);
            sreg = s[(size_t)tl * NB * DS + (size_t)b * DS + scol];
        }

        for (int tt = 0; tt < CHUNK; ++tt) {
            // ---- phase 1: Wz[h] = W1 row · z (LDS broadcast, 2-way = free) ----
            const float4* z4 = (const float4*)(z_sh + half * 32);
            float a0 = 0.f, a1 = 0.f, a2 = 0.f, a3 = 0.f;
            #pragma unroll
            for (int k = 0; k < 8; ++k) {
                float4 zv = z4[k];
                a0 = fmaf(w1v[k].x, zv.x, a0);
                a1 = fmaf(w1v[k].y, zv.y, a1);
                a2 = fmaf(w1v[k].z, zv.z, a2);
                a3 = fmaf(w1v[k].w, zv.w, a3);
            }
            float p1 = (a0 + a1) + (a2 + a3);
            p1 = dpp_add<0xB1>(p1);       // combine even/odd halves (quad_perm xor1)
            float za = fmaxf(p1 + h1r, 0.f) - fmaxf(p1, 0.f);
            if (half == 0) za_sh[zi] = za;
            barrier_lgkm();               // A: za_sh (+ s_sh at chunk start) visible

            // ---- phase 2: row computes z_new[j0], z_new[j1] over full h ----
            const float4* q4 = (const float4*)(za_sh + 20 * r4);  // skewed 16-slice
            float sv = s_sh[tt * DS + r4];                        // this lane's s element
            float p00 = c0 * sv, p01 = 0.f, p02 = 0.f, p03 = 0.f; // fold C·s into rotation
            float p10 = c1 * sv, p11 = 0.f, p12 = 0.f, p13 = 0.f;
            #pragma unroll
            for (int k = 0; k < 4; ++k) {
                float4 v = q4[k];
                p00 = fmaf(w2a[k].x, v.x, p00);
                p01 = fmaf(w2a[k].y, v.y, p01);
                p02 = fmaf(w2a[k].z, v.z, p02);
                p03 = fmaf(w2a[k].w, v.w, p03);
                p10 = fmaf(w2b[k].x, v.x, p10);
                p11 = fmaf(w2b[k].y, v.y, p11);
                p12 = fmaf(w2b[k].z, v.z, p12);
                p13 = fmaf(w2b[k].w, v.w, p13);
            }
            float pa = (p00 + p01) + (p02 + p03);
            float pb = (p10 + p11) + (p12 + p13);
            pa = row16_allsum(pa);        // VALU DPP rotation reduce (no LDS)
            pb = row16_allsum(pb);

            // ---- epilogue: every lane of the row holds both full sums ----
            float zn0 = fmaf(A0, zr0, pa + h20);
            float zn1 = fmaf(A1, zr1, pb + h21);
            zr0 = zn0; zr1 = zn1;
            const int t = t0 + tt;
            if (r4 < 2) {
                float zsel = (r4 == 0) ? zn0 : zn1;
                z_sh[j0 + r4] = zsel;
                if (t < T_STEPS)
                    out[(size_t)t * NB * DZ + (size_t)b * DZ + j0 + r4] = zsel;
            }
            barrier_lgkm();               // B: z_sh update visible for next phase 1
        }
    }
}

extern "C" void kernel_launch(void* const* d_in, const int* in_sizes, int n_in,
                              void* d_out, int out_size, void* d_ws, size_t ws_size,
                              hipStream_t stream) {
    const float* z0p = (const float*)d_in[0];
    const float* sp  = (const float*)d_in[1];
    const float* Ap  = (const float*)d_in[2];
    const float* W1p = (const float*)d_in[3];
    const float* W2p = (const float*)d_in[4];
    const float* h1p = (const float*)d_in[5];
    const float* h2p = (const float*)d_in[6];
    const float* Cp  = (const float*)d_in[7];

    plrnn_scan<<<dim3(NB), dim3(512), 0, stream>>>(z0p, sp, Ap, W1p, W2p, h1p, h2p, Cp,
                                                   (float*)d_out);
}